// Round 3
// baseline (336.529 us; speedup 1.0000x reference)
//
#include <hip/hip_runtime.h>

// Problem: B=16384, F=1024, H=64, D=256, TE=CE=4.
// I/O dtype: float32 (per reference). Internal compute: fp16 MFMA, fp32 accum.
// out = (outA, outS, outB), each [B, 256] fp32, concatenated in d_out.

#define BB 16384
#define FF 1024

typedef _Float16 f16;
typedef __fp16 h16x2 __attribute__((ext_vector_type(2)));   // cvt_pkrtz return type
typedef _Float16 f16x8 __attribute__((ext_vector_type(8)));
typedef float f32x4 __attribute__((ext_vector_type(4)));

// async global->LDS, 16B per lane. LDS dest must be wave-uniform base + lane*16.
__device__ __forceinline__ void load_lds16(const void* g, void* l) {
    __builtin_amdgcn_global_load_lds(
        (const __attribute__((address_space(1))) unsigned int*)g,
        (__attribute__((address_space(3))) unsigned int*)l, 16, 0, 0);
}

__device__ __forceinline__ f16x8 pack8(float4 lo, float4 hi) {
    union { f16x8 v; h16x2 p[4]; } u;
    u.p[0] = __builtin_amdgcn_cvt_pkrtz(lo.x, lo.y);
    u.p[1] = __builtin_amdgcn_cvt_pkrtz(lo.z, lo.w);
    u.p[2] = __builtin_amdgcn_cvt_pkrtz(hi.x, hi.y);
    u.p[3] = __builtin_amdgcn_cvt_pkrtz(hi.z, hi.w);
    return u.v;
}

// ---------------------------------------------------------------------------
// Pack: Wp[g][c][k] = (f16)W1g[e=c>>6][k][h=c&63]     (3 x 256 x 1024)
//       W2T[g][e][d][h] = (f16)W2g[e][h][d]           (3 x 4 x 256 x 64)
//       Gp[g][k][c16]  = (f16)Wgg[k][c] (zero-pad)    (3 x 1024 x 16)
// ---------------------------------------------------------------------------
__global__ __launch_bounds__(256) void pack_kernel(
    const float* __restrict__ W1A, const float* __restrict__ W1S, const float* __restrict__ W1B,
    const float* __restrict__ W2A, const float* __restrict__ W2S, const float* __restrict__ W2B,
    const float* __restrict__ WgA, const float* __restrict__ WgS, const float* __restrict__ WgB,
    f16* __restrict__ Wp, f16* __restrict__ W2T, f16* __restrict__ Gp)
{
    int idx = blockIdx.x * 256 + threadIdx.x;
    if (idx < 786432) {
        int g = idx / 262144, rem = idx % 262144;
        int c = rem >> 10, k = rem & 1023;
        const float* W1 = (g == 0) ? W1A : ((g == 1) ? W1S : W1B);
        Wp[idx] = (f16)W1[((c >> 6) << 16) + k * 64 + (c & 63)];
    } else if (idx < 983040) {
        int j = idx - 786432;
        int g = j / 65536, rem = j % 65536;
        int e = rem >> 14, rr = rem & 16383;
        int d = rr >> 6, hh = rr & 63;
        const float* W2 = (g == 0) ? W2A : ((g == 1) ? W2S : W2B);
        W2T[j] = (f16)W2[e * 16384 + hh * 256 + d];
    } else {
        int j = idx - 983040;                 // < 3*16384
        int g = j / 16384, rem = j % 16384;
        int k = rem >> 4, c = rem & 15;
        int ng = (g == 1) ? 12 : 8;
        const float* Wg = (g == 0) ? WgA : ((g == 1) ? WgS : WgB);
        Gp[j] = (c < ng) ? (f16)Wg[k * ng + c] : (f16)0.0f;
    }
}

// ---------------------------------------------------------------------------
// Layer-1: h_g = relu(x_g @ W1cat_g + b1_g)  -> fp16 h [3][B][256]
// plus fused gate softmax on blockIdx.x==0: gates fp32.
// 128x128 tile, BK=32, mfma_f32_16x16x32_f16. grid (2, 128, 3), block 256.
// A staged as raw fp32 (16 KB/iter), converted to f16 at fragment read.
// XOR segment swizzles keep LDS reads at free 2-way aliasing.
// ---------------------------------------------------------------------------
__global__ __launch_bounds__(256) void l1_kernel(
    const float* __restrict__ xA, const float* __restrict__ xS, const float* __restrict__ xB,
    const float* __restrict__ b1A, const float* __restrict__ b1S, const float* __restrict__ b1B,
    const float* __restrict__ bgA, const float* __restrict__ bgS, const float* __restrict__ bgB,
    const f16* __restrict__ Wp,      // [3][256][1024]
    const f16* __restrict__ Gp,      // [3][1024][16]
    f16* __restrict__ hbuf,          // [3][B][256]
    float* __restrict__ gates)       // gA[B][8] | gS[B][12] | gB[B][8]
{
    const int g = blockIdx.z;
    const float* x  = (g == 0) ? xA  : ((g == 1) ? xS  : xB);
    const float* b1 = (g == 0) ? b1A : ((g == 1) ? b1S : b1B);
    const float* bg = (g == 0) ? bgA : ((g == 1) ? bgS : bgB);
    const int ng = (g == 1) ? 12 : 8;
    float* gout = gates + ((g == 0) ? (size_t)0
                         : (g == 1) ? (size_t)BB * 8
                                    : (size_t)BB * 8 + (size_t)BB * 12);

    const int row0 = blockIdx.y * 128;
    const int col0 = blockIdx.x * 128;
    const bool do_gate = (blockIdx.x == 0);

    __shared__ __align__(16) float Asf[128 * 32];   // fp32 x tile, swizzled segs
    __shared__ __align__(16) f16   Bsh[128 * 32];   // f16 weights [n][k], swizzled
    __shared__ __align__(16) f16   Gs[16 * 40];     // gate weights [c][k], padded ld

    const int tid  = threadIdx.x;
    const int lane = tid & 63;
    const int wave = tid >> 6;
    const int wm = (wave >> 1) * 64;
    const int wn = (wave & 1) * 64;
    const int lrow = lane & 15;
    const int quad = lane >> 4;

    const f16* Wgrp = Wp + (size_t)g * 256 * 1024;
    const f16* Ggrp = Gp + (size_t)g * 1024 * 16;

    f32x4 acc[4][4] = {};
    f32x4 gacc[4] = {};
    const bool my_gate = do_gate && ((wave & 1) == 0);

    for (int k0 = 0; k0 < FF; k0 += 32) {
        // A: 1024 segs (16 KB fp32), 4 rounds. seg stored at slot = seg^(m&7).
#pragma unroll
        for (int r = 0; r < 4; ++r) {
            int s = r * 256 + tid;
            int m = s >> 3, slot = s & 7;
            int seg = slot ^ (m & 7);
            load_lds16(x + (size_t)(row0 + m) * FF + k0 + seg * 4, Asf + s * 4);
        }
        // B: 512 segs (8 KB f16), 2 rounds. slot = seg^((m>>1)&3).
#pragma unroll
        for (int r = 0; r < 2; ++r) {
            int s = r * 256 + tid;
            int m = s >> 2, slot = s & 3;
            int seg = slot ^ ((m >> 1) & 3);
            load_lds16(Wgrp + (size_t)(col0 + m) * FF + k0 + seg * 8, Bsh + s * 8);
        }
        if (do_gate) {
#pragma unroll
            for (int r = 0; r < 2; ++r) {
                int idx = r * 256 + tid;          // 0..511
                int k = idx >> 4, c = idx & 15;
                Gs[c * 40 + k] = Ggrp[(size_t)(k0 + k) * 16 + c];
            }
        }
        __syncthreads();

        f16x8 af[4], bfr[4];
#pragma unroll
        for (int i = 0; i < 4; ++i) {
            int m = wm + i * 16 + lrow;
            const float* rp = Asf + m * 32;
            int s0 = (2 * quad) ^ (m & 7);
            int s1 = s0 ^ 1;
            float4 lo = *(const float4*)(rp + s0 * 4);   // k = q*8 .. q*8+3
            float4 hi = *(const float4*)(rp + s1 * 4);   // k = q*8+4 .. q*8+7
            // NOTE: s1 = s0^1 means (2q) even→lo at s0, hi at s0+1. seg index
            // determines k-chunk: seg s covers k = s*4 .. s*4+3. We need
            // k = quad*8..quad*8+7 => segs 2q and 2q+1. slot(2q)=2q^(m&7),
            // slot(2q+1)=(2q+1)^(m&7) = slot(2q)^1. Correct.
            af[i] = pack8(lo, hi);
        }
#pragma unroll
        for (int j = 0; j < 4; ++j) {
            int n = wn + j * 16 + lrow;
            int slot = quad ^ ((n >> 1) & 3);
            bfr[j] = *(const f16x8*)(Bsh + n * 32 + slot * 8);
        }
#pragma unroll
        for (int i = 0; i < 4; ++i)
#pragma unroll
            for (int j = 0; j < 4; ++j)
                acc[i][j] = __builtin_amdgcn_mfma_f32_16x16x32_f16(af[i], bfr[j], acc[i][j], 0, 0, 0);
        if (my_gate) {
            f16x8 gb = *(const f16x8*)(Gs + lrow * 40 + quad * 8);
#pragma unroll
            for (int i = 0; i < 4; ++i)
                gacc[i] = __builtin_amdgcn_mfma_f32_16x16x32_f16(af[i], gb, gacc[i], 0, 0, 0);
        }
        __syncthreads();
    }

    // epilogue: h = relu(acc + b1), fp16. C/D: col=lane&15, row=quad*4+reg.
#pragma unroll
    for (int j = 0; j < 4; ++j) {
        int c = col0 + wn + j * 16 + lrow;       // packed col == e*64+h == b1 flat idx
        float bias = b1[c];
#pragma unroll
        for (int i = 0; i < 4; ++i) {
#pragma unroll
            for (int r = 0; r < 4; ++r) {
                int row = row0 + wm + i * 16 + quad * 4 + r;
                float v = fmaxf(acc[i][j][r] + bias, 0.0f);
                hbuf[((size_t)g * BB + row) * 256 + c] = (f16)v;
            }
        }
    }

    // gate softmax: 16-lane groups share one row's logits (c = lrow)
    if (my_gate) {
        int c = lrow;
        bool valid = (c < ng);
        float bias = valid ? bg[c] : 0.0f;
#pragma unroll
        for (int i = 0; i < 4; ++i) {
#pragma unroll
            for (int r = 0; r < 4; ++r) {
                int row = row0 + wm + i * 16 + quad * 4 + r;
                float logit = valid ? (gacc[i][r] + bias) : -1e30f;
                float mx = logit;
#pragma unroll
                for (int m = 1; m < 16; m <<= 1)
                    mx = fmaxf(mx, __shfl_xor(mx, m, 16));
                float ev = valid ? __expf(logit - mx) : 0.0f;
                float sum = ev;
#pragma unroll
                for (int m = 1; m < 16; m <<= 1)
                    sum += __shfl_xor(sum, m, 16);
                if (valid) gout[(size_t)row * ng + c] = ev / sum;
            }
        }
    }
}

// ---------------------------------------------------------------------------
// Layer-2 + gated combine. grid (256, 3), block 256.
// Each block: 64 rows x 256 cols of one output; loops its 8/12 contributing
// (group, expert) pairs, staging h-slice [64x64] + W2T [256x64] per pair.
// ---------------------------------------------------------------------------
__global__ __launch_bounds__(256) void l2_kernel(
    const f16* __restrict__ hbuf,    // [3][B][256]
    const f16* __restrict__ W2T,     // [3][4][256][64]
    const float* __restrict__ b2A, const float* __restrict__ b2S, const float* __restrict__ b2B,
    const float* __restrict__ gates,
    float* __restrict__ out)         // [3][B][256] (A,S,B)
{
    const int o = blockIdx.y;
    const int row0 = blockIdx.x * 64;
    const int tid = threadIdx.x;
    const int lane = tid & 63;
    const int wave = tid >> 6;
    const int wn = wave * 64;
    const int lrow = lane & 15;
    const int quad = lane >> 4;

    const int ng = (o == 1) ? 12 : 8;
    const float* gp = gates + ((o == 0) ? (size_t)0
                             : (o == 1) ? (size_t)BB * 8
                                        : (size_t)BB * 8 + (size_t)BB * 12);

    __shared__ __align__(16) f16 Ash[64 * 64];      // h slice [m][k], swizzled
    __shared__ __align__(16) f16 Bsh[256 * 64];     // W2T [d][k], swizzled
    __shared__ float gsh[64 * 12];

    for (int idx = tid; idx < 64 * ng; idx += 256)
        gsh[idx] = gp[(size_t)(row0 + idx / ng) * ng + (idx % ng)];

    f32x4 oacc[4][4] = {};
    const int nc = ng;

    for (int k = 0; k < nc; ++k) {
        int e = k & 3, gc = k, gi;
        if (o == 0)      gi = (k < 4) ? 0 : 1;   // concat([EA, ES])
        else if (o == 1) gi = k >> 2;            // concat([EA, ES, EB])
        else             gi = (k < 4) ? 2 : 1;   // concat([EB, ES])

        const f16* hs = hbuf + ((size_t)gi * BB + row0) * 256 + e * 64;
        const f16* w2 = W2T + (size_t)(gi * 4 + e) * 256 * 64;
        const float* b2 = (gi == 0) ? b2A : ((gi == 1) ? b2S : b2B);

        __syncthreads();   // LDS reuse fence (covers gsh writes on iter 0)
#pragma unroll
        for (int r = 0; r < 2; ++r) {            // h slice: 512 segs
            int s = r * 256 + tid;
            int m = s >> 3, slot = s & 7;
            int seg = slot ^ (m & 7);
            load_lds16(hs + (size_t)m * 256 + seg * 8, Ash + s * 8);
        }
#pragma unroll
        for (int r = 0; r < 8; ++r) {            // W2T: 2048 segs
            int s = r * 256 + tid;
            int m = s >> 3, slot = s & 7;
            int seg = slot ^ (m & 7);
            load_lds16(w2 + (size_t)m * 64 + seg * 8, Bsh + s * 8);
        }
        __syncthreads();

        f32x4 eacc[4][4] = {};
#pragma unroll
        for (int kk = 0; kk < 2; ++kk) {
            f16x8 af[4], bfr[4];
#pragma unroll
            for (int i = 0; i < 4; ++i) {
                int rr = i * 16 + lrow;
                int slot = (kk * 4 + quad) ^ (rr & 7);
                af[i] = *(const f16x8*)(Ash + rr * 64 + slot * 8);
            }
#pragma unroll
            for (int j = 0; j < 4; ++j) {
                int n = wn + j * 16 + lrow;
                int slot = (kk * 4 + quad) ^ (n & 7);
                bfr[j] = *(const f16x8*)(Bsh + n * 64 + slot * 8);
            }
#pragma unroll
            for (int i = 0; i < 4; ++i)
#pragma unroll
                for (int j = 0; j < 4; ++j)
                    eacc[i][j] = __builtin_amdgcn_mfma_f32_16x16x32_f16(af[i], bfr[j], eacc[i][j], 0, 0, 0);
        }

        // oacc += gate[row] * relu(eacc + b2)
#pragma unroll
        for (int j = 0; j < 4; ++j) {
            int d = wn + j * 16 + lrow;
            float bias = b2[e * 256 + d];
#pragma unroll
            for (int i = 0; i < 4; ++i) {
#pragma unroll
                for (int r = 0; r < 4; ++r) {
                    int rl = i * 16 + quad * 4 + r;
                    float v = fmaxf(eacc[i][j][r] + bias, 0.0f);
                    oacc[i][j][r] += gsh[rl * ng + gc] * v;
                }
            }
        }
    }

#pragma unroll
    for (int j = 0; j < 4; ++j) {
        int d = wn + j * 16 + lrow;
#pragma unroll
        for (int i = 0; i < 4; ++i) {
#pragma unroll
            for (int r = 0; r < 4; ++r) {
                int rl = i * 16 + quad * 4 + r;
                out[((size_t)o * BB + row0 + rl) * 256 + d] = oacc[i][j][r];
            }
        }
    }
}

// ---------------------------------------------------------------------------
extern "C" void kernel_launch(void* const* d_in, const int* in_sizes, int n_in,
                              void* d_out, int out_size, void* d_ws, size_t ws_size,
                              hipStream_t stream)
{
    (void)in_sizes; (void)n_in; (void)out_size; (void)ws_size;

    const float* xA  = (const float*)d_in[0];
    const float* xS  = (const float*)d_in[1];
    const float* xB  = (const float*)d_in[2];
    const float* W1A = (const float*)d_in[3];
    const float* b1A = (const float*)d_in[4];
    const float* W2A = (const float*)d_in[5];
    const float* b2A = (const float*)d_in[6];
    const float* W1S = (const float*)d_in[7];
    const float* b1S = (const float*)d_in[8];
    const float* W2S = (const float*)d_in[9];
    const float* b2S = (const float*)d_in[10];
    const float* W1B = (const float*)d_in[11];
    const float* b1B = (const float*)d_in[12];
    const float* W2B = (const float*)d_in[13];
    const float* b2B = (const float*)d_in[14];
    const float* WgA = (const float*)d_in[15];
    const float* bgA = (const float*)d_in[16];
    const float* WgB = (const float*)d_in[17];
    const float* bgB = (const float*)d_in[18];
    const float* WgS = (const float*)d_in[19];
    const float* bgS = (const float*)d_in[20];

    char* ws = (char*)d_ws;
    f16*   Wp   = (f16*)(ws);                       // 1,572,864 B
    f16*   W2T  = (f16*)(ws + 0x180000);            //   393,216 B
    f16*   Gp   = (f16*)(ws + 0x1E0000);            //    98,304 B
    f16*   hbuf = (f16*)(ws + 0x200000);            // 25,165,824 B
    float* gate = (float*)(ws + 0x200000 + 0x1800000); // 1,835,008 B

    pack_kernel<<<4032, 256, 0, stream>>>(W1A, W1S, W1B, W2A, W2S, W2B,
                                          WgA, WgS, WgB, Wp, W2T, Gp);
    l1_kernel<<<dim3(2, 128, 3), 256, 0, stream>>>(
        xA, xS, xB, b1A, b1S, b1B, bgA, bgS, bgB,
        Wp, Gp, hbuf, gate);
    l2_kernel<<<dim3(256, 3), 256, 0, stream>>>(
        hbuf, W2T, b2A, b2S, b2B, gate, (float*)d_out);
}